// Round 10
// baseline (1638.976 us; speedup 1.0000x reference)
//
#include <hip/hip_runtime.h>
#include <math.h>

typedef _Float16 f16;
typedef _Float16 f16x4 __attribute__((ext_vector_type(4)));
typedef _Float16 f16x8 __attribute__((ext_vector_type(8)));
typedef float    f32x16 __attribute__((ext_vector_type(16)));

#define N_ROWS 16000
#define DIM    256
#define BATCH  4096
#define TK     32       // kv rows per tile
#define NTILE  500      // 16000/32
#define TPS    250      // tiles per KV slice (2 slices)
#define QT     64       // Q rows per block (2 waves x 32 rows)
#define LTP    72       // pack-transpose LDS pad

// Image layouts (written by k_pack — R6-verified — read by k_attn), per 16 KB tile:
//   K tile (32 kv x 256 d):  byte(r,c)  = r*512 + ((c*2) ^ ((r&7)<<4))
//   V tile (256 d x 32 kv):  byte(d,kv) = (d>>1)*128 + (((d&1)*64 + kv*2) ^ (((d>>1)&7)<<4))
//   P tile (32 q  x 32 kv):  byte(q,kv) = q*128 + ((kv*2) ^ ((q&7)<<4))   (per-wave)
// All b128 reads: every consecutive-8-lane phase is an XOR-bijection onto 8
// distinct 16B slots (all 32 banks) -> conflict-free. P stores are 8B, 4-way max.

// ---------------- pack: fp32 -> f16 swizzled image tiles (K + V^T) — R6 verbatim ----------------
__global__ __launch_bounds__(256) void k_pack(
    const float* __restrict__ m0, const float* __restrict__ m1, const float* __restrict__ m2,
    const float* __restrict__ m3, const float* __restrict__ m4, const float* __restrict__ m5,
    unsigned char* __restrict__ Kimg, unsigned char* __restrict__ Vimg)
{
  __shared__ f16 lt[64][LTP];   // [n-local][d-local]
  const float* mats[6] = {m0, m1, m2, m3, m4, m5};
  int bid = blockIdx.x;                 // 6 * 250 * 4
  int db  = bid & 3;                    // d block (64 cols)
  int tn  = (bid >> 2) % 250;           // 64-row group (spans 2 TK=32 tiles)
  int me  = bid / (250 * 4);
  const float* src = mats[me];
  int tid = threadIdx.x;
#pragma unroll
  for (int i = 0; i < 4; ++i) {
    int cidx = i * 256 + tid;           // 1024 chunks of 4 floats: 64 rows x 16 chunks
    int r = cidx >> 4, cc = (cidx & 15) * 4;
    float4 f = *(const float4*)(src + (size_t)(tn * 64 + r) * DIM + db * 64 + cc);
    f16x4 h = {(f16)f.x, (f16)f.y, (f16)f.z, (f16)f.w};
    *(f16x4*)&lt[r][cc] = h;
    size_t g = (size_t)(me * NTILE + tn * 2 + (r >> 5)) << 14;
    *(f16x4*)(Kimg + g + (r & 31) * 512 + (((db * 64 + cc) * 2) ^ ((r & 7) << 4))) = h;
  }
  __syncthreads();
#pragma unroll
  for (int i = 0; i < 4; ++i) {
    int cidx = i * 256 + tid;           // 64 d x 16 kv-chunks
    int dl = cidx >> 4, nc4 = (cidx & 15) * 4;
    f16x4 hv = { lt[nc4 + 0][dl], lt[nc4 + 1][dl], lt[nc4 + 2][dl], lt[nc4 + 3][dl] };
    size_t g = (size_t)(me * NTILE + tn * 2 + (nc4 >> 5)) << 14;
    int kvl = nc4 & 31;
    int dp  = db * 32 + (dl >> 1);      // (d>>1); (d>>1)&7 == (dl>>1)&7
    int inner = (dl & 1) * 64 + kvl * 2;
    *(f16x4*)(Vimg + g + dp * 128 + (inner ^ (((dl >> 1) & 7) << 4))) = hv;
  }
}

// ---------------- gather Q rows to f16 ----------------
__global__ __launch_bounds__(256) void k_gather(
    const float* __restrict__ m0, const float* __restrict__ m1, const float* __restrict__ m2,
    const float* __restrict__ m3, const float* __restrict__ m4, const float* __restrict__ m5,
    const int* __restrict__ batch, f16* __restrict__ Qg)
{
  const float* mats[6] = {m0, m1, m2, m3, m4, m5};
  int gid  = blockIdx.x * 4 + (threadIdx.x >> 6);   // row id 0..24575 (cs*4096+b)
  int lane = threadIdx.x & 63;
  int s   = gid / (3 * BATCH);
  int rem = gid - s * 3 * BATCH;
  int c   = rem / BATCH;
  int b   = rem - c * BATCH;
  int idx = batch[(size_t)b * 2 + s];               // int32 per harness contract
  const float* src = mats[(s == 0 ? 0 : 3) + c] + (size_t)idx * DIM;
  float4 f = *(const float4*)(src + lane * 4);
  f16x4 h = {(f16)f.x, (f16)f.y, (f16)f.z, (f16)f.w};
  *(f16x4*)(Qg + (size_t)gid * DIM + lane * 4) = h;
}

// -- flash attention: swapped-operand 32x32 MFMA, 2-wave blocks, M=32/wave, TK=32 --
// sacc = mfma_32x32x16(A=kf, B=qf) -> S^T[kv32][q32]; lane holds col q=lane&31,
// rows kv=(r&3)+8*(r>>2)+4*hi (r=reg 0..15, hi=lane>>5): 16 of 32 kv; partner
// lane (l^32) holds the other 16 at the SAME q -> row reduce = in-lane + ONE
// shfl_xor(32). PV: O^T = mfma(A=vf, B=pf) per 32-d block; P round-trips via a
// tiny per-wave swizzled LDS tile to redistribute kv across the hi-halves.
__global__ __launch_bounds__(128, 2) void k_attn(
    const unsigned char* __restrict__ Kimg, const unsigned char* __restrict__ Vimg,
    const f16* __restrict__ Qg, f16* __restrict__ Onorm, float* __restrict__ ml)
{
  __shared__ unsigned char shK[16384];      // 32 kv x 256 d  (swizzled image)
  __shared__ unsigned char shV[16384];      // 256 d x 32 kv  (swizzled image)
  __shared__ unsigned char shP[2][4096];    // per-wave P: 32 q x 32 kv (swizzled, 128B rows)
  // total 40,960 B -> 3 resident blocks/CU at grid=768 (6 waves/CU)

  const int bid = blockIdx.x;               // 768 = 6(cs) * 64(qtile) * 2(slice)
  const int v  = bid & 1;
  const int t  = (bid >> 1) & 63;
  const int cs = bid >> 7;                  // s*3+c
  const int s  = cs / 3, c = cs - s * 3;
  const int kvmat = (s == 0) ? (3 + c) : c;

  const int tid  = threadIdx.x;             // 0..127 (2 waves)
  const int lane = tid & 63;
  const int w    = tid >> 6;                // wave id 0..1
  const int l31  = lane & 31;
  const int hi   = lane >> 5;
  const int xr   = (l31 & 7) << 4;          // XOR key (row&7 == l31&7 in all tiles)
  unsigned char* Pw = shP[w];

  // Q fragments (B-operand: n=q=l31, k=hi*8+j per 16-step): lane holds Q-row
  // q = base + l31, d in {ks*16 + hi*8 .. +7} -> 16 x f16x8 = 32 VGPRs
  const f16* Qrow = Qg + ((size_t)cs * BATCH + (size_t)t * QT + w * 32 + l31) * DIM + hi * 8;
  f16x8 qf[16];
#pragma unroll
  for (int ks = 0; ks < 16; ++ks) qf[ks] = *(const f16x8*)(Qrow + ks * 16);

  f32x16 O[8];                              // O^T: [d = db*32+(r&3)+8*(r>>2)+4*hi][q=l31]
#pragma unroll
  for (int i = 0; i < 8; ++i) O[i] = (f32x16)(0.f);
  float m_r = -INFINITY;
  float l_r = 0.f;

  const unsigned char* gK0 = Kimg + ((size_t)(kvmat * NTILE) << 14);
  const unsigned char* gV0 = Vimg + ((size_t)(kvmat * NTILE) << 14);

  for (int tile = v * TPS; tile < v * TPS + TPS; ++tile) {
    { // ---- stage K then V: global uint4 -> linear LDS write (conflict-free) ----
      const uint4* gK = (const uint4*)(gK0 + ((size_t)tile << 14));
      const uint4* gV = (const uint4*)(gV0 + ((size_t)tile << 14));
      uint4 st[8];
#pragma unroll
      for (int i = 0; i < 8; ++i) st[i] = gK[i * 128 + tid];
#pragma unroll
      for (int i = 0; i < 8; ++i) *(uint4*)(shK + (i * 128 + tid) * 16) = st[i];
#pragma unroll
      for (int i = 0; i < 8; ++i) st[i] = gV[i * 128 + tid];
#pragma unroll
      for (int i = 0; i < 8; ++i) *(uint4*)(shV + (i * 128 + tid) * 16) = st[i];
    }
    __syncthreads();

    // ---- S^T = K Q^T : 16 MFMA (32x32x16), K-dim 256 = 16 steps ----
    f32x16 sacc = (f32x16)(0.f);
#pragma unroll
    for (int ks = 0; ks < 16; ++ks) {
      // A = K[kv=l31][d = ks*16 + hi*8 + j]
      f16x8 kf = *(const f16x8*)(shK + l31 * 512 + ((ks * 32 + hi * 16) ^ xr));
      sacc = __builtin_amdgcn_mfma_f32_32x32x16_f16(kf, qf[ks], sacc, 0, 0, 0);
    }

    // ---- online softmax: in-lane reduce over 16 + ONE cross-half shuffle ----
    float mx = sacc[0];
#pragma unroll
    for (int r = 1; r < 16; ++r) mx = fmaxf(mx, sacc[r]);
    mx = fmaxf(mx, __shfl_xor(mx, 32, 64));
    float mnew = fmaxf(m_r, mx);
    float alpha = __expf(m_r - mnew);   // 0 on first tile, 1 when max unchanged
    bool upd = (mnew > m_r);
    m_r = mnew;

    float rowsum = 0.f;
#pragma unroll
    for (int rq = 0; rq < 4; ++rq) {
      f16x4 pk;
#pragma unroll
      for (int j = 0; j < 4; ++j) {
        float p = __expf(sacc[rq * 4 + j] - m_r);
        rowsum += p;
        pk[j] = (f16)p;
      }
      // P[q=l31][kv = rq*8 + hi*4 + j] -> byte = q*128 + ((kv*2) ^ xr)
      *(f16x4*)(Pw + l31 * 128 + ((rq * 16 + hi * 8) ^ xr)) = pk;
    }
    rowsum += __shfl_xor(rowsum, 32, 64);
    l_r = l_r * alpha + rowsum;

    if (__any(upd)) {                    // rare after early tiles
#pragma unroll
      for (int i = 0; i < 8; ++i) O[i] *= alpha;
    }

    // ---- O^T += V^T P : wave-local shP (same-wave ds ops in-order, no barrier) ----
    // B = P: lane provides k = kv = ks*16 + hi*8 + j, n = q = l31
    f16x8 pf[2];
#pragma unroll
    for (int ks = 0; ks < 2; ++ks)
      pf[ks] = *(const f16x8*)(Pw + l31 * 128 + ((ks * 32 + hi * 16) ^ xr));
#pragma unroll
    for (int db = 0; db < 8; ++db) {
#pragma unroll
      for (int ks = 0; ks < 2; ++ks) {
        // A = V^T[d = db*32 + l31][kv = ks*16 + hi*8 + j] per R6's V image layout
        f16x8 vf = *(const f16x8*)(shV + (db * 16 + (l31 >> 1)) * 128 +
                                   (((l31 & 1) * 64 + ks * 32 + hi * 16) ^ (((l31 >> 1) & 7) << 4)));
        O[db] = __builtin_amdgcn_mfma_f32_32x32x16_f16(vf, pf[ks], O[db], 0, 0, 0);
      }
    }
    __syncthreads();   // all waves done reading shK/shV before next tile's writes
  }

  // ---- epilogue: per-slice normalized O + (m,l); lane owns q-row l31 ----
  const size_t orow = (size_t)(v * 6 + cs) * BATCH + (size_t)t * QT + w * 32 + l31;
  if (hi == 0) {
    ml[orow * 2 + 0] = m_r;
    ml[orow * 2 + 1] = l_r;
  }
  float inv = 1.0f / l_r;
#pragma unroll
  for (int db = 0; db < 8; ++db) {
#pragma unroll
    for (int rq = 0; rq < 4; ++rq) {
      f16x4 ov = {(f16)(O[db][rq * 4 + 0] * inv), (f16)(O[db][rq * 4 + 1] * inv),
                  (f16)(O[db][rq * 4 + 2] * inv), (f16)(O[db][rq * 4 + 3] * inv)};
      int d = db * 32 + rq * 8 + hi * 4;   // rows (r&3)+8*rq+4*hi, j consecutive
      *(f16x4*)(Onorm + orow * DIM + d) = ov;
    }
  }
}

// ---------------- combine slices + residual + MLP -> sigmoid scalar ----------------
__global__ __launch_bounds__(256, 2) void k_combine(
    const float* __restrict__ W1, const float* __restrict__ b1,
    const float* __restrict__ W2, const float* __restrict__ b2,
    const f16* __restrict__ Qg, const f16* __restrict__ Onorm,
    const float* __restrict__ ml, float* __restrict__ mval)
{
  __shared__ f16 w1s[DIM * 128];
  __shared__ float reb[4][DIM];
  __shared__ float w2s[128];
  __shared__ float b1s[128];
  int tid = threadIdx.x;
#pragma unroll
  for (int i = 0; i < 32; ++i) {
    int e = i * 1024 + tid * 4;
    float4 f = *(const float4*)(W1 + e);
    f16x4 h = {(f16)f.x, (f16)f.y, (f16)f.z, (f16)f.w};
    *(f16x4*)&w1s[e] = h;
  }
  if (tid < 128) { w2s[tid] = W2[tid]; b1s[tid] = b1[tid]; }
  float b2v = b2[0];
  __syncthreads();

  int w = tid >> 6, lane = tid & 63;
  for (int rr = 0; rr < 8; ++rr) {
    int grow = blockIdx.x * 32 + w * 8 + rr;       // cs*4096+q, 0..24575
    float m0 = ml[grow * 2],            l0 = ml[grow * 2 + 1];
    float m1 = ml[(24576 + grow) * 2],  l1 = ml[(24576 + grow) * 2 + 1];
    float M  = fmaxf(m0, m1);
    float w0  = l0 * __expf(m0 - M);
    float w1v = l1 * __expf(m1 - M);
    float inv = 1.f / (w0 + w1v);
    w0 *= inv; w1v *= inv;
    f16x4 o0 = *(const f16x4*)(Onorm + (size_t)grow * DIM + lane * 4);
    f16x4 o1 = *(const f16x4*)(Onorm + (size_t)(24576 + grow) * DIM + lane * 4);
    f16x4 qv = *(const f16x4*)(Qg + (size_t)grow * DIM + lane * 4);
#pragma unroll
    for (int k = 0; k < 4; ++k)
      reb[w][lane * 4 + k] = w0 * (float)o0[k] + w1v * (float)o1[k] + (float)qv[k];
    // wave-local LDS use: same-wave ds ops are in-order, no barrier needed
    float acc0 = b1s[lane], acc1 = b1s[lane + 64];
    for (int d = 0; d < DIM; ++d) {
      float rv = reb[w][d];                       // broadcast read
      acc0 += rv * (float)w1s[d * 128 + lane];
      acc1 += rv * (float)w1s[d * 128 + 64 + lane];
    }
    float part = fmaxf(acc0, 0.f) * w2s[lane] + fmaxf(acc1, 0.f) * w2s[lane + 64];
#pragma unroll
    for (int off = 1; off < 64; off <<= 1) part += __shfl_xor(part, off, 64);
    if (lane == 0) mval[grow] = 1.f / (1.f + __expf(-(part + b2v)));
  }
}

// ---------------- copy all 6 arrays to out ----------------
__global__ __launch_bounds__(256) void k_copy(
    const float* __restrict__ m0, const float* __restrict__ m1, const float* __restrict__ m2,
    const float* __restrict__ m3, const float* __restrict__ m4, const float* __restrict__ m5,
    float* __restrict__ out)
{
  const float* mats[6] = {m0, m1, m2, m3, m4, m5};
  int arr = blockIdx.x / 4000;
  int chunk = (blockIdx.x - arr * 4000) * 256 + threadIdx.x;   // float4 index in array
  float4 v = *(const float4*)(mats[arr] + (size_t)chunk * 4);
  *(float4*)(out + (size_t)arr * 4096000 + (size_t)chunk * 4) = v;
}

// ---------------- kg softmax + scaled row scatter ----------------
__global__ __launch_bounds__(256) void k_scatter(
    const float* __restrict__ m0, const float* __restrict__ m1, const float* __restrict__ m2,
    const float* __restrict__ m3, const float* __restrict__ m4, const float* __restrict__ m5,
    const int* __restrict__ batch, const float* __restrict__ mval,
    float* __restrict__ out)
{
  const float* mats[6] = {m0, m1, m2, m3, m4, m5};
  int gid  = blockIdx.x * 4 + (threadIdx.x >> 6);   // 0..8191 = s*4096+b
  int lane = threadIdx.x & 63;
  int s = gid >> 12;
  int b = gid & 4095;
  int idx = batch[(size_t)b * 2 + s];
  float v0 = mval[(s * 3 + 0) * BATCH + b];
  float v1 = mval[(s * 3 + 1) * BATCH + b];
  float v2 = mval[(s * 3 + 2) * BATCH + b];
  float mx = fmaxf(v0, fmaxf(v1, v2));
  float e0 = __expf(v0 - mx), e1 = __expf(v1 - mx), e2 = __expf(v2 - mx);
  float inv = 1.f / (e0 + e1 + e2);
  float kgn = e1 * inv;   // channel 1: x_name
  float kgo = e2 * inv;   // channel 2: onehot
  int a1 = s * 3 + 1, a2 = s * 3 + 2;
  const float* s1 = mats[a1] + (size_t)idx * DIM;
  const float* s2 = mats[a2] + (size_t)idx * DIM;
  float4 f1 = *(const float4*)(s1 + lane * 4);
  float4 f2 = *(const float4*)(s2 + lane * 4);
  float4 r1 = {f1.x * kgn, f1.y * kgn, f1.z * kgn, f1.w * kgn};
  float4 r2 = {f2.x * kgo, f2.y * kgo, f2.z * kgo, f2.w * kgo};
  *(float4*)(out + (size_t)a1 * 4096000 + (size_t)idx * DIM + lane * 4) = r1;
  *(float4*)(out + (size_t)a2 * 4096000 + (size_t)idx * DIM + lane * 4) = r2;
}

extern "C" void kernel_launch(void* const* d_in, const int* in_sizes, int n_in,
                              void* d_out, int out_size, void* d_ws, size_t ws_size,
                              hipStream_t stream)
{
  const float* x1  = (const float*)d_in[0];
  const float* xn1 = (const float*)d_in[1];
  const float* oh1 = (const float*)d_in[2];
  const float* x2  = (const float*)d_in[3];
  const float* xn2 = (const float*)d_in[4];
  const float* oh2 = (const float*)d_in[5];
  const float* W1  = (const float*)d_in[6];
  const float* b1  = (const float*)d_in[7];
  const float* W2  = (const float*)d_in[8];
  const float* b2  = (const float*)d_in[9];
  const int*   batch = (const int*)d_in[10];   // int32 per harness contract
  float* out = (float*)d_out;

  // Big packed K/V scratch lives in d_out (exact fit: 98,304,000 B), and is
  // consumed entirely before k_copy overwrites d_out with real outputs.
  // Both images are stored as per-tile 16 KB swizzled LDS images (TK=32).
  unsigned char* Kimg = (unsigned char*)d_out;                 // 6*500*16384 = 49,152,000 B
  unsigned char* Vimg = (unsigned char*)d_out + 49152000;      // 6*500*16384 = 49,152,000 B

  // d_ws: 38,240,256 B total
  char* ws = (char*)d_ws;
  f16*   Qg    = (f16*)(ws);                 // 24576*256 f16    = 12,582,912 B
  f16*   Onorm = (f16*)(ws + 12582912);      // 2*24576*256 f16  = 25,165,824 B
  float* ml    = (float*)(ws + 37748736);    // 2*24576*2 f32    =    393,216 B
  float* mval  = (float*)(ws + 38141952);    // 24576 f32        =     98,304 B

  k_pack   <<<6000, 256, 0, stream>>>(x1, xn1, oh1, x2, xn2, oh2, Kimg, Vimg);
  k_gather <<<6144, 256, 0, stream>>>(x1, xn1, oh1, x2, xn2, oh2, batch, Qg);
  k_attn   <<<768,  128, 0, stream>>>(Kimg, Vimg, Qg, Onorm, ml);
  k_combine<<<768,  256, 0, stream>>>(W1, b1, W2, b2, Qg, Onorm, ml, mval);
  k_copy   <<<24000, 256, 0, stream>>>(x1, xn1, oh1, x2, xn2, oh2, out);
  k_scatter<<<2048, 256, 0, stream>>>(x1, xn1, oh1, x2, xn2, oh2, batch, mval, out);
}

// Round 11
// 951.930 us; speedup vs baseline: 1.7217x; 1.7217x over previous
//
#include <hip/hip_runtime.h>
#include <math.h>

typedef _Float16 f16;
typedef _Float16 f16x4 __attribute__((ext_vector_type(4)));
typedef _Float16 f16x8 __attribute__((ext_vector_type(8)));
typedef float    f32x4 __attribute__((ext_vector_type(4)));

#define N_ROWS 16000
#define DIM    256
#define BATCH  4096
#define TK     64
#define NTILE  250      // 16000/64
#define TPS    125      // tiles per KV slice (2 slices)
#define LTP    72       // pack-transpose LDS pad
#define PPAD   72       // P row stride in f16 (144 B), R8-verified

// Image layouts (written by k_pack — R4-verified — read by k_attn), 32 KB tiles:
//   K tile (64 kv x 256 d): byte(r,c)  = r*512 + ((c*2) ^ ((r&7)<<4))
//   V tile (256 d x 64 kv): byte(d,kv) = d*128 + ((kv*2) ^ ((d&7)<<4))
// XOR flips byte-bits 4..6 -> 16B chunks move wholesale. Wave b128 reads at a
// fixed column spread every 8-lane phase over 8 distinct 16B slots (all 32
// banks even) -> conflict-free. Staging writes are linear tid*16 -> conflict-free.

// ---------------- pack: fp32 -> f16 swizzled image tiles (K + V^T) — R4 verbatim ----------------
__global__ __launch_bounds__(256) void k_pack(
    const float* __restrict__ m0, const float* __restrict__ m1, const float* __restrict__ m2,
    const float* __restrict__ m3, const float* __restrict__ m4, const float* __restrict__ m5,
    unsigned char* __restrict__ Kimg, unsigned char* __restrict__ Vimg)
{
  __shared__ f16 lt[64][LTP];   // [n-local][d-local]
  const float* mats[6] = {m0, m1, m2, m3, m4, m5};
  int bid = blockIdx.x;                 // 6 * 250 * 4
  int db  = bid & 3;                    // d block (64 cols)
  int tn  = (bid >> 2) % NTILE;         // n tile (64 rows)
  int me  = bid / (NTILE * 4);
  const float* src = mats[me];
  int tid = threadIdx.x;
  unsigned char* Kt = Kimg + ((size_t)(me * NTILE + tn) << 15);
  unsigned char* Vt = Vimg + ((size_t)(me * NTILE + tn) << 15);
#pragma unroll
  for (int i = 0; i < 4; ++i) {
    int cidx = i * 256 + tid;           // 1024 chunks of 4 floats: 64 rows x 16 chunks
    int r = cidx >> 4, cc = (cidx & 15) * 4;
    float4 f = *(const float4*)(src + (size_t)(tn * 64 + r) * DIM + db * 64 + cc);
    f16x4 h = {(f16)f.x, (f16)f.y, (f16)f.z, (f16)f.w};
    *(f16x4*)&lt[r][cc] = h;
    *(f16x4*)(Kt + r * 512 + ((db * 128 + cc * 2) ^ ((r & 7) << 4))) = h;
  }
  __syncthreads();
#pragma unroll
  for (int i = 0; i < 4; ++i) {
    int cidx = i * 256 + tid;           // 64 d x 16 n-chunks
    int dl = cidx >> 4, nc4 = (cidx & 15) * 4;
    f16x4 hv = { lt[nc4 + 0][dl], lt[nc4 + 1][dl], lt[nc4 + 2][dl], lt[nc4 + 3][dl] };
    int d = db * 64 + dl;               // d&7 == dl&7
    *(f16x4*)(Vt + d * 128 + ((nc4 * 2) ^ ((dl & 7) << 4))) = hv;
  }
}

// ---------------- gather Q rows to f16 ----------------
__global__ __launch_bounds__(256) void k_gather(
    const float* __restrict__ m0, const float* __restrict__ m1, const float* __restrict__ m2,
    const float* __restrict__ m3, const float* __restrict__ m4, const float* __restrict__ m5,
    const int* __restrict__ batch, f16* __restrict__ Qg)
{
  const float* mats[6] = {m0, m1, m2, m3, m4, m5};
  int gid  = blockIdx.x * 4 + (threadIdx.x >> 6);   // row id 0..24575 (cs*4096+b)
  int lane = threadIdx.x & 63;
  int s   = gid / (3 * BATCH);
  int rem = gid - s * 3 * BATCH;
  int c   = rem / BATCH;
  int b   = rem - c * BATCH;
  int idx = batch[(size_t)b * 2 + s];               // int32 per harness contract
  const float* src = mats[(s == 0 ? 0 : 3) + c] + (size_t)idx * DIM;
  float4 f = *(const float4*)(src + lane * 4);
  f16x4 h = {(f16)f.x, (f16)f.y, (f16)f.z, (f16)f.w};
  *(f16x4*)(Qg + (size_t)gid * DIM + lane * 4) = h;
}

// -- flash attention (f16 MFMA): R8 body (swapped-operand softmax) + image LDS --
// Swapped QK^T: sacc = mfma(A=kf, B=qf) -> S^T[kv][q]; lane holds q=l15,
// kv = nc*16 + quad*4 + r. Row-reduce = in-lane + 2 shfl_xor. PV swapped:
// O^T = mfma(A=vf, B=pf); O layout [d][q]: d = nc*16+quad*4+r, q = l15.
__global__ __launch_bounds__(256, 2) void k_attn(
    const unsigned char* __restrict__ Kimg, const unsigned char* __restrict__ Vimg,
    const f16* __restrict__ Qg, f16* __restrict__ Onorm, float* __restrict__ ml)
{
  __shared__ unsigned char shK[32768];   // 64 kv x 256 d  (swizzled image)
  __shared__ unsigned char shV[32768];   // 256 d x 64 kv  (swizzled image)
  __shared__ f16 shP[4][16][PPAD];       // per-wave P^T [q][kv] (16 x 64, padded; R8)
  // total 74,752 B -> 2 blocks/CU

  const int bid = blockIdx.x;         // 768 = 6(cs) * 64(qtile) * 2(slice)
  const int v  = bid & 1;
  const int t  = (bid >> 1) & 63;
  const int cs = bid >> 7;            // s*3+c
  const int s  = cs / 3, c = cs - s * 3;
  const int kvmat = (s == 0) ? (3 + c) : c;

  const int tid  = threadIdx.x;
  const int lane = tid & 63;
  const int w    = tid >> 6;
  const int l15  = lane & 15;
  const int quad = lane >> 4;
  const int xr   = (l15 & 7) << 4;    // read-side XOR (row&7 == l15&7 everywhere)

  // Q fragments in registers (B-operand layout: n=q=l15, k=quad*8+j) — R8 verbatim
  const f16* Qrow = Qg + ((size_t)cs * BATCH + (size_t)t * 64 + w * 16 + l15) * DIM + quad * 8;
  f16x8 qf[8];
#pragma unroll
  for (int kt = 0; kt < 8; ++kt) qf[kt] = *(const f16x8*)(Qrow + kt * 32);

  f32x4 O[16];                        // O^T fragment: [d = nc*16+quad*4+r][q=l15]
#pragma unroll
  for (int i = 0; i < 16; ++i) O[i] = (f32x4){0.f, 0.f, 0.f, 0.f};
  float m_r = -INFINITY;              // running max of this lane's q-row
  float l_r = 0.f;                    // running denom

  const unsigned char* gK0 = Kimg + ((size_t)(kvmat * NTILE) << 15);
  const unsigned char* gV0 = Vimg + ((size_t)(kvmat * NTILE) << 15);

  for (int tile = v * TPS; tile < v * TPS + TPS; ++tile) {
    { // ---- stage K then V: image uint4 -> LINEAR LDS write (conflict-free) ----
      const uint4* gK = (const uint4*)(gK0 + ((size_t)tile << 15));
      const uint4* gV = (const uint4*)(gV0 + ((size_t)tile << 15));
      uint4 st[8];
#pragma unroll
      for (int i = 0; i < 8; ++i) st[i] = gK[i * 256 + tid];
#pragma unroll
      for (int i = 0; i < 8; ++i) *(uint4*)(shK + i * 4096 + tid * 16) = st[i];
#pragma unroll
      for (int i = 0; i < 8; ++i) st[i] = gV[i * 256 + tid];
#pragma unroll
      for (int i = 0; i < 8; ++i) *(uint4*)(shV + i * 4096 + tid * 16) = st[i];
    }
    __syncthreads();

    // ---- S^T = K Q^T : per lane 16 kv-values of q-row l15 ----
    f32x4 sacc[4];
#pragma unroll
    for (int nc = 0; nc < 4; ++nc) sacc[nc] = (f32x4){0.f, 0.f, 0.f, 0.f};
#pragma unroll
    for (int kt = 0; kt < 8; ++kt) {
#pragma unroll
      for (int nc = 0; nc < 4; ++nc) {
        f16x8 kf = *(const f16x8*)(shK + (nc * 16 + l15) * 512 + ((kt * 64 + quad * 16) ^ xr));
        sacc[nc] = __builtin_amdgcn_mfma_f32_16x16x32_f16(kf, qf[kt], sacc[nc], 0, 0, 0);
      }
    }

    // ---- online softmax: in-lane reduce + 2 cross-quad shuffles (R8) ----
    float mx = sacc[0][0];
#pragma unroll
    for (int nc = 0; nc < 4; ++nc)
#pragma unroll
      for (int r = 0; r < 4; ++r) mx = fmaxf(mx, sacc[nc][r]);
    mx = fmaxf(mx, __shfl_xor(mx, 16, 64));
    mx = fmaxf(mx, __shfl_xor(mx, 32, 64));
    float mnew = fmaxf(m_r, mx);
    float alpha = __expf(m_r - mnew);   // 0 on first tile, 1 when max unchanged
    bool upd = (mnew > m_r);
    m_r = mnew;

    float rowsum = 0.f;
#pragma unroll
    for (int nc = 0; nc < 4; ++nc) {
      f16x4 pk;
#pragma unroll
      for (int r = 0; r < 4; ++r) {
        float p = __expf(sacc[nc][r] - m_r);
        rowsum += p;
        pk[r] = (f16)p;
      }
      // P^T store: row q=l15, kv = nc*16 + quad*4 .. +3 (8B aligned, <=2-way banks)
      *(f16x4*)&shP[w][l15][nc * 16 + quad * 4] = pk;
    }
    rowsum += __shfl_xor(rowsum, 16, 64);
    rowsum += __shfl_xor(rowsum, 32, 64);
    l_r = l_r * alpha + rowsum;

    if (__any(upd)) {                    // rare after early tiles
#pragma unroll
      for (int nc = 0; nc < 16; ++nc) O[nc] *= alpha;
    }

    // ---- O^T += V^T P^T (wave-local shP: same-wave ds ops in-order, no barrier) ----
    f16x8 pf0 = *(const f16x8*)&shP[w][l15][quad * 8];
    f16x8 pf1 = *(const f16x8*)&shP[w][l15][32 + quad * 8];
#pragma unroll
    for (int nc = 0; nc < 16; ++nc) {
      f16x8 vf0 = *(const f16x8*)(shV + (nc * 16 + l15) * 128 + ((quad * 16) ^ xr));
      O[nc] = __builtin_amdgcn_mfma_f32_16x16x32_f16(vf0, pf0, O[nc], 0, 0, 0);
      f16x8 vf1 = *(const f16x8*)(shV + (nc * 16 + l15) * 128 + ((64 + quad * 16) ^ xr));
      O[nc] = __builtin_amdgcn_mfma_f32_16x16x32_f16(vf1, pf1, O[nc], 0, 0, 0);
    }
    __syncthreads();
  }

  // ---- epilogue: per-slice normalized O + (m,l); lane owns q-row l15 ----
  const size_t orow = (size_t)(v * 6 + cs) * BATCH + (size_t)t * 64 + w * 16 + l15;
  if (quad == 0) {
    ml[orow * 2 + 0] = m_r;
    ml[orow * 2 + 1] = l_r;
  }
  float inv = 1.0f / l_r;
#pragma unroll
  for (int nc = 0; nc < 16; ++nc) {
    f16x4 ov = {(f16)(O[nc][0] * inv), (f16)(O[nc][1] * inv),
                (f16)(O[nc][2] * inv), (f16)(O[nc][3] * inv)};
    *(f16x4*)(Onorm + orow * DIM + nc * 16 + quad * 4) = ov;
  }
}

// ---------------- combine slices + residual + MLP -> sigmoid scalar ----------------
__global__ __launch_bounds__(256, 2) void k_combine(
    const float* __restrict__ W1, const float* __restrict__ b1,
    const float* __restrict__ W2, const float* __restrict__ b2,
    const f16* __restrict__ Qg, const f16* __restrict__ Onorm,
    const float* __restrict__ ml, float* __restrict__ mval)
{
  __shared__ f16 w1s[DIM * 128];
  __shared__ float reb[4][DIM];
  __shared__ float w2s[128];
  __shared__ float b1s[128];
  int tid = threadIdx.x;
#pragma unroll
  for (int i = 0; i < 32; ++i) {
    int e = i * 1024 + tid * 4;
    float4 f = *(const float4*)(W1 + e);
    f16x4 h = {(f16)f.x, (f16)f.y, (f16)f.z, (f16)f.w};
    *(f16x4*)&w1s[e] = h;
  }
  if (tid < 128) { w2s[tid] = W2[tid]; b1s[tid] = b1[tid]; }
  float b2v = b2[0];
  __syncthreads();

  int w = tid >> 6, lane = tid & 63;
  for (int rr = 0; rr < 8; ++rr) {
    int grow = blockIdx.x * 32 + w * 8 + rr;       // cs*4096+q, 0..24575
    float m0 = ml[grow * 2],            l0 = ml[grow * 2 + 1];
    float m1 = ml[(24576 + grow) * 2],  l1 = ml[(24576 + grow) * 2 + 1];
    float M  = fmaxf(m0, m1);
    float w0  = l0 * __expf(m0 - M);
    float w1v = l1 * __expf(m1 - M);
    float inv = 1.f / (w0 + w1v);
    w0 *= inv; w1v *= inv;
    f16x4 o0 = *(const f16x4*)(Onorm + (size_t)grow * DIM + lane * 4);
    f16x4 o1 = *(const f16x4*)(Onorm + (size_t)(24576 + grow) * DIM + lane * 4);
    f16x4 qv = *(const f16x4*)(Qg + (size_t)grow * DIM + lane * 4);
#pragma unroll
    for (int k = 0; k < 4; ++k)
      reb[w][lane * 4 + k] = w0 * (float)o0[k] + w1v * (float)o1[k] + (float)qv[k];
    // wave-local LDS use: same-wave ds ops are in-order, no barrier needed
    float acc0 = b1s[lane], acc1 = b1s[lane + 64];
    for (int d = 0; d < DIM; ++d) {
      float rv = reb[w][d];                       // broadcast read
      acc0 += rv * (float)w1s[d * 128 + lane];
      acc1 += rv * (float)w1s[d * 128 + 64 + lane];
    }
    float part = fmaxf(acc0, 0.f) * w2s[lane] + fmaxf(acc1, 0.f) * w2s[lane + 64];
#pragma unroll
    for (int off = 1; off < 64; off <<= 1) part += __shfl_xor(part, off, 64);
    if (lane == 0) mval[grow] = 1.f / (1.f + __expf(-(part + b2v)));
  }
}

// ---------------- copy all 6 arrays to out ----------------
__global__ __launch_bounds__(256) void k_copy(
    const float* __restrict__ m0, const float* __restrict__ m1, const float* __restrict__ m2,
    const float* __restrict__ m3, const float* __restrict__ m4, const float* __restrict__ m5,
    float* __restrict__ out)
{
  const float* mats[6] = {m0, m1, m2, m3, m4, m5};
  int arr = blockIdx.x / 4000;
  int chunk = (blockIdx.x - arr * 4000) * 256 + threadIdx.x;   // float4 index in array
  float4 v = *(const float4*)(mats[arr] + (size_t)chunk * 4);
  *(float4*)(out + (size_t)arr * 4096000 + (size_t)chunk * 4) = v;
}

// ---------------- kg softmax + scaled row scatter ----------------
__global__ __launch_bounds__(256) void k_scatter(
    const float* __restrict__ m0, const float* __restrict__ m1, const float* __restrict__ m2,
    const float* __restrict__ m3, const float* __restrict__ m4, const float* __restrict__ m5,
    const int* __restrict__ batch, const float* __restrict__ mval,
    float* __restrict__ out)
{
  const float* mats[6] = {m0, m1, m2, m3, m4, m5};
  int gid  = blockIdx.x * 4 + (threadIdx.x >> 6);   // 0..8191 = s*4096+b
  int lane = threadIdx.x & 63;
  int s = gid >> 12;
  int b = gid & 4095;
  int idx = batch[(size_t)b * 2 + s];
  float v0 = mval[(s * 3 + 0) * BATCH + b];
  float v1 = mval[(s * 3 + 1) * BATCH + b];
  float v2 = mval[(s * 3 + 2) * BATCH + b];
  float mx = fmaxf(v0, fmaxf(v1, v2));
  float e0 = __expf(v0 - mx), e1 = __expf(v1 - mx), e2 = __expf(v2 - mx);
  float inv = 1.f / (e0 + e1 + e2);
  float kgn = e1 * inv;   // channel 1: x_name
  float kgo = e2 * inv;   // channel 2: onehot
  int a1 = s * 3 + 1, a2 = s * 3 + 2;
  const float* s1 = mats[a1] + (size_t)idx * DIM;
  const float* s2 = mats[a2] + (size_t)idx * DIM;
  float4 f1 = *(const float4*)(s1 + lane * 4);
  float4 f2 = *(const float4*)(s2 + lane * 4);
  float4 r1 = {f1.x * kgn, f1.y * kgn, f1.z * kgn, f1.w * kgn};
  float4 r2 = {f2.x * kgo, f2.y * kgo, f2.z * kgo, f2.w * kgo};
  *(float4*)(out + (size_t)a1 * 4096000 + (size_t)idx * DIM + lane * 4) = r1;
  *(float4*)(out + (size_t)a2 * 4096000 + (size_t)idx * DIM + lane * 4) = r2;
}

extern "C" void kernel_launch(void* const* d_in, const int* in_sizes, int n_in,
                              void* d_out, int out_size, void* d_ws, size_t ws_size,
                              hipStream_t stream)
{
  const float* x1  = (const float*)d_in[0];
  const float* xn1 = (const float*)d_in[1];
  const float* oh1 = (const float*)d_in[2];
  const float* x2  = (const float*)d_in[3];
  const float* xn2 = (const float*)d_in[4];
  const float* oh2 = (const float*)d_in[5];
  const float* W1  = (const float*)d_in[6];
  const float* b1  = (const float*)d_in[7];
  const float* W2  = (const float*)d_in[8];
  const float* b2  = (const float*)d_in[9];
  const int*   batch = (const int*)d_in[10];   // int32 per harness contract
  float* out = (float*)d_out;

  // Big packed K/V scratch lives in d_out (exact fit: 98,304,000 B), and is
  // consumed entirely before k_copy overwrites d_out with real outputs.
  // Both images are stored as per-tile 32 KB swizzled LDS images.
  unsigned char* Kimg = (unsigned char*)d_out;                 // 6*250*32768 = 49,152,000 B
  unsigned char* Vimg = (unsigned char*)d_out + 49152000;      // 6*250*32768 = 49,152,000 B

  // d_ws: 38,240,256 B total
  char* ws = (char*)d_ws;
  f16*   Qg    = (f16*)(ws);                 // 24576*256 f16    = 12,582,912 B
  f16*   Onorm = (f16*)(ws + 12582912);      // 2*24576*256 f16  = 25,165,824 B
  float* ml    = (float*)(ws + 37748736);    // 2*24576*2 f32    =    393,216 B
  float* mval  = (float*)(ws + 38141952);    // 24576 f32        =     98,304 B

  k_pack   <<<6000, 256, 0, stream>>>(x1, xn1, oh1, x2, xn2, oh2, Kimg, Vimg);
  k_gather <<<6144, 256, 0, stream>>>(x1, xn1, oh1, x2, xn2, oh2, batch, Qg);
  k_attn   <<<768,  256, 0, stream>>>(Kimg, Vimg, Qg, Onorm, ml);
  k_combine<<<768,  256, 0, stream>>>(W1, b1, W2, b2, Qg, Onorm, ml, mval);
  k_copy   <<<24000, 256, 0, stream>>>(x1, xn1, oh1, x2, xn2, oh2, out);
  k_scatter<<<2048, 256, 0, stream>>>(x1, xn1, oh1, x2, xn2, oh2, batch, mval, out);
}